// Round 1
// baseline (248.654 us; speedup 1.0000x reference)
//
#include <hip/hip_runtime.h>
#include <stdint.h>

#define N 8192
#define DIM 128
#define NCLS 10

typedef __attribute__((ext_vector_type(8))) short short8;
typedef __attribute__((ext_vector_type(4))) float f32x4;

static __device__ __forceinline__ unsigned short f2bf(float x) {
    unsigned u = __float_as_uint(x);
    unsigned r = (u + 0x7FFFu + ((u >> 16) & 1u)) >> 16;  // RNE
    return (unsigned short)r;
}

// Kernel 1: bf16 conversion (B = bf16(E), A = bf16(-2E)), sq[i], per-class sumsq & count.
__global__ __launch_bounds__(256) void prep_kernel(
    const float* __restrict__ emb, const int* __restrict__ labels,
    unsigned short* __restrict__ Abuf, unsigned short* __restrict__ Bbuf,
    float* __restrict__ sq, float* __restrict__ sumsq_c, int* __restrict__ cnt)
{
    int wid = threadIdx.x >> 6, lane = threadIdx.x & 63;
    int row = blockIdx.x * 4 + wid;
    const float2 e = *(const float2*)(emb + (size_t)row * DIM + lane * 2);
    unsigned bb = (unsigned)f2bf(e.x) | ((unsigned)f2bf(e.y) << 16);
    unsigned ab = (unsigned)f2bf(-2.f * e.x) | ((unsigned)f2bf(-2.f * e.y) << 16);
    *(unsigned*)(Bbuf + (size_t)row * DIM + lane * 2) = bb;
    *(unsigned*)(Abuf + (size_t)row * DIM + lane * 2) = ab;
    float s = e.x * e.x + e.y * e.y;
    #pragma unroll
    for (int d = 1; d < 64; d <<= 1) s += __shfl_xor(s, d);
    if (lane == 0) {
        int lab = labels[row];
        sq[row] = s;
        atomicAdd(&sumsq_c[lab], s);
        atomicAdd(&cnt[lab], 1);
    }
}

// Kernel 2: s_c[c][d] = sum over class-c rows of emb[:, d]
__global__ __launch_bounds__(128) void class_sum_kernel(
    const float* __restrict__ emb, const int* __restrict__ labels,
    float* __restrict__ s_c)
{
    int c = blockIdx.x;
    int base = blockIdx.y * 128;
    int d = threadIdx.x;
    float acc = 0.f;
    for (int r = 0; r < 128; ++r) {
        int i = base + r;
        float v = emb[(size_t)i * DIM + d];
        if (labels[i] == c) acc += v;
    }
    atomicAdd(&s_c[c * DIM + d], acc);
}

// Kernel 3: first-10 (smallest original index) members of class 0 and class 1.
__global__ void meta_kernel(const int* __restrict__ labels, int* __restrict__ lists)
{
    int lane = threadIdx.x & 63;
    for (int c = 0; c < 2; ++c) {
        int cnt = 0;
        for (int base = 0; base < N && cnt < 10; base += 64) {
            int lab = labels[base + lane];
            unsigned long long m = __ballot(lab == c);
            while (m && cnt < 10) {
                int b = __ffsll((unsigned long long)m) - 1;
                if (lane == 0) lists[c * 10 + cnt] = base + b;
                cnt++;
                m &= m - 1;
            }
        }
    }
}

// Kernel 4: masked Gram argmax. C = (-2E)·E^T via bf16 MFMA; val = sq[j] + C[i][j];
// per-row argmax over same-class cols, tie -> smallest j. One atomicMax per row per block.
__global__ __launch_bounds__(256, 2) void gram_kernel(
    const unsigned short* __restrict__ Abuf, const unsigned short* __restrict__ Bbuf,
    const float* __restrict__ sq, const int* __restrict__ labels,
    unsigned long long* __restrict__ packed)
{
    __shared__ __align__(16) unsigned short As[128 * 128]; // 32KB, full K, swizzled
    __shared__ __align__(16) unsigned short Bs[128 * 64];  // 16KB, half K, swizzled
    const int tid = threadIdx.x;
    const int lane = tid & 63;
    const int wid = tid >> 6;
    const int wr = wid >> 1, wc = wid & 1;       // 2x2 waves, each 64 rows x 64 cols
    const int rowbase = blockIdx.x * 128;
    const int stripbase = blockIdx.y * 1024;     // 8 strips x 1024 cols

    // Stage A once: tile is a contiguous 32KB block of Abuf.
    {
        const char* src = (const char*)(Abuf + (size_t)rowbase * DIM);
        #pragma unroll
        for (int p = 0; p < 8; ++p) {
            int o = (p * 256 + tid) * 16;
            uint4 v = *(const uint4*)(src + o);
            *(uint4*)((char*)As + (o ^ (((o >> 8) & 7) << 4))) = v;
        }
    }

    int labA[4][4];
    #pragma unroll
    for (int m = 0; m < 4; ++m)
        #pragma unroll
        for (int r = 0; r < 4; ++r)
            labA[m][r] = labels[rowbase + wr * 64 + m * 16 + (lane >> 4) * 4 + r];

    unsigned long long best[4][4];
    #pragma unroll
    for (int m = 0; m < 4; ++m)
        #pragma unroll
        for (int r = 0; r < 4; ++r) best[m][r] = 0ull;

    for (int ct = 0; ct < 8; ++ct) {
        const int colbase = stripbase + ct * 128;
        f32x4 acc[4][4];
        #pragma unroll
        for (int m = 0; m < 4; ++m)
            #pragma unroll
            for (int n = 0; n < 4; ++n) acc[m][n] = (f32x4){0.f, 0.f, 0.f, 0.f};

        #pragma unroll
        for (int kh = 0; kh < 2; ++kh) {
            __syncthreads();  // guard Bs overwrite vs prior reads
            #pragma unroll
            for (int p = 0; p < 4; ++p) {
                int o = (p * 256 + tid) * 16;
                int col = o >> 7, kb = o & 127;
                uint4 v = *(const uint4*)((const char*)(Bbuf + (size_t)(colbase + col) * DIM) + kh * 128 + kb);
                *(uint4*)((char*)Bs + (o ^ (((o >> 7) & 7) << 4))) = v;
            }
            __syncthreads();
            #pragma unroll
            for (int kk = 0; kk < 2; ++kk) {
                int kloc = kk * 32 + (lane >> 4) * 8;
                short8 a[4], b[4];
                #pragma unroll
                for (int m = 0; m < 4; ++m) {
                    int row = wr * 64 + m * 16 + (lane & 15);
                    int byt = row * 256 + (kh * 64 + kloc) * 2;
                    a[m] = *(const short8*)((const char*)As + (byt ^ ((row & 7) << 4)));
                }
                #pragma unroll
                for (int n = 0; n < 4; ++n) {
                    int col = wc * 64 + n * 16 + (lane & 15);
                    int byt = col * 128 + kloc * 2;
                    b[n] = *(const short8*)((const char*)Bs + (byt ^ ((col & 7) << 4)));
                }
                #pragma unroll
                for (int m = 0; m < 4; ++m)
                    #pragma unroll
                    for (int n = 0; n < 4; ++n)
                        acc[m][n] = __builtin_amdgcn_mfma_f32_16x16x32_bf16(a[m], b[n], acc[m][n], 0, 0, 0);
            }
        }
        // Epilogue: val = acc + sq[col]; masked packed-max update (registers only).
        #pragma unroll
        for (int n = 0; n < 4; ++n) {
            int colg = colbase + wc * 64 + n * 16 + (lane & 15);
            int labB = labels[colg];
            float sqv = sq[colg];
            unsigned long long idxbits = (unsigned long long)(~(unsigned)colg & 0xFFFFFFFFu);
            #pragma unroll
            for (int m = 0; m < 4; ++m)
                #pragma unroll
                for (int r = 0; r < 4; ++r) {
                    if (labA[m][r] == labB) {
                        float val = acc[m][n][r] + sqv;
                        unsigned u = __float_as_uint(val);
                        unsigned key = (u & 0x80000000u) ? ~u : (u | 0x80000000u);
                        unsigned long long pk = ((unsigned long long)key << 32) | idxbits;
                        if (pk > best[m][r]) best[m][r] = pk;
                    }
                }
        }
    }
    // Cross-lane reduce over the 16 columns-groups, then one atomic per row.
    #pragma unroll
    for (int m = 0; m < 4; ++m)
        #pragma unroll
        for (int r = 0; r < 4; ++r) {
            unsigned long long v = best[m][r];
            #pragma unroll
            for (int d = 1; d < 16; d <<= 1) {
                unsigned long long o = __shfl_xor(v, d);
                if (o > v) v = o;
            }
            if ((lane & 15) == 0 && v)
                atomicMax(&packed[rowbase + wr * 64 + m * 16 + (lane >> 4) * 4 + r], v);
        }
}

// Kernel 5: per-anchor j* via class aggregates, exact fp32 distances, loss sum.
__global__ __launch_bounds__(1024) void loss_kernel(
    const float* __restrict__ emb, const int* __restrict__ labels,
    const float* __restrict__ sq, const float* __restrict__ s_c,
    const float* __restrict__ sumsq_c, const int* __restrict__ cnt,
    const int* __restrict__ lists, const unsigned long long* __restrict__ packed,
    float* __restrict__ out)
{
    __shared__ float sc[NCLS * DIM];
    __shared__ float wsum[16];
    int tid = threadIdx.x;
    for (int p = tid; p < NCLS * DIM; p += 1024) sc[p] = s_c[p];
    __syncthreads();
    int wid = tid >> 6, lane = tid & 63;
    int i = blockIdx.x * 16 + wid;
    float2 e = *(const float2*)(emb + (size_t)i * DIM + lane * 2);
    float dots[NCLS];
    #pragma unroll
    for (int c = 0; c < NCLS; ++c)
        dots[c] = e.x * sc[c * DIM + lane * 2] + e.y * sc[c * DIM + lane * 2 + 1];
    #pragma unroll
    for (int d = 1; d < 64; d <<= 1) {
        #pragma unroll
        for (int c = 0; c < NCLS; ++c) dots[c] += __shfl_xor(dots[c], d);
    }
    float sqi = sq[i];
    int li = labels[i];
    // argmin_c negdist == argmax_c classsum (row-sum cancels); ties -> smallest c.
    float bestv = -3.4e38f; int js = 0;
    #pragma unroll
    for (int c = 0; c < NCLS; ++c) {
        float v = (float)cnt[c] * sqi + sumsq_c[c] - 2.f * dots[c];
        if (v > bestv) { bestv = v; js = c; }
    }
    int wn = lists[(li == 0 ? 10 : 0) + js];
    int wp = (int)(~(unsigned)packed[i]);  // low 32 bits hold ~j
    float2 ep = *(const float2*)(emb + (size_t)wp * DIM + lane * 2);
    float2 en = *(const float2*)(emb + (size_t)wn * DIM + lane * 2);
    float px = e.x - ep.x, py = e.y - ep.y;
    float nx = e.x - en.x, ny = e.y - en.y;
    float dp = px * px + py * py;
    float dn = nx * nx + ny * ny;
    #pragma unroll
    for (int d = 1; d < 64; d <<= 1) { dp += __shfl_xor(dp, d); dn += __shfl_xor(dn, d); }
    if (lane == 0) {
        float t = dp - dn + 1.0f;
        wsum[wid] = t > 0.f ? t : 0.f;
    }
    __syncthreads();
    if (tid == 0) {
        float s = 0.f;
        #pragma unroll
        for (int w = 0; w < 16; ++w) s += wsum[w];
        atomicAdd(out, s);
    }
}

extern "C" void kernel_launch(void* const* d_in, const int* in_sizes, int n_in,
                              void* d_out, int out_size, void* d_ws, size_t ws_size,
                              hipStream_t stream)
{
    const float* emb = (const float*)d_in[0];
    const int* labels = (const int*)d_in[1];
    char* ws = (char*)d_ws;

    unsigned short* Abuf = (unsigned short*)(ws);                                // 2 MB
    unsigned short* Bbuf = (unsigned short*)(ws + (size_t)2 * 1024 * 1024);      // 2 MB
    float* sq = (float*)(ws + (size_t)4 * 1024 * 1024);                          // 32 KB
    size_t zoff = (size_t)4 * 1024 * 1024 + 32 * 1024;
    unsigned long long* packed = (unsigned long long*)(ws + zoff);               // 64 KB
    float* s_c = (float*)(ws + zoff + 64 * 1024);                                // 5 KB
    float* sumsq_c = (float*)((char*)s_c + NCLS * DIM * sizeof(float));
    int* cnt = (int*)((char*)sumsq_c + NCLS * sizeof(float));
    int* lists = (int*)((char*)cnt + NCLS * sizeof(int));
    size_t zsz = 64 * 1024 + NCLS * DIM * sizeof(float) + NCLS * sizeof(float)
               + NCLS * sizeof(int) + 20 * sizeof(int);

    hipMemsetAsync(ws + zoff, 0, zsz, stream);
    hipMemsetAsync(d_out, 0, sizeof(float), stream);

    prep_kernel<<<2048, 256, 0, stream>>>(emb, labels, Abuf, Bbuf, sq, sumsq_c, cnt);
    class_sum_kernel<<<dim3(10, 64), 128, 0, stream>>>(emb, labels, s_c);
    meta_kernel<<<1, 64, 0, stream>>>(labels, lists);
    gram_kernel<<<dim3(64, 8), 256, 0, stream>>>(Abuf, Bbuf, sq, labels, packed);
    loss_kernel<<<512, 1024, 0, stream>>>(emb, labels, sq, s_c, sumsq_c, cnt, lists, packed,
                                          (float*)d_out);
}

// Round 2
// 108.087 us; speedup vs baseline: 2.3005x; 2.3005x over previous
//
#include <hip/hip_runtime.h>
#include <stdint.h>

#define N 8192
#define DIM 128
#define NCLS 10

typedef __attribute__((ext_vector_type(8))) short short8;
typedef __attribute__((ext_vector_type(4))) float f32x4;

static __device__ __forceinline__ unsigned short f2bf(float x) {
    unsigned u = __float_as_uint(x);
    unsigned r = (u + 0x7FFFu + ((u >> 16) & 1u)) >> 16;  // RNE
    return (unsigned short)r;
}

// Kernel 1: bf16 conversion (B = bf16(E), A = bf16(-2E)) and sq[i]. NO atomics.
__global__ __launch_bounds__(256) void prep_kernel(
    const float* __restrict__ emb,
    unsigned short* __restrict__ Abuf, unsigned short* __restrict__ Bbuf,
    float* __restrict__ sq)
{
    int wid = threadIdx.x >> 6, lane = threadIdx.x & 63;
    int row = blockIdx.x * 4 + wid;
    const float2 e = *(const float2*)(emb + (size_t)row * DIM + lane * 2);
    unsigned bb = (unsigned)f2bf(e.x) | ((unsigned)f2bf(e.y) << 16);
    unsigned ab = (unsigned)f2bf(-2.f * e.x) | ((unsigned)f2bf(-2.f * e.y) << 16);
    *(unsigned*)(Bbuf + (size_t)row * DIM + lane * 2) = bb;
    *(unsigned*)(Abuf + (size_t)row * DIM + lane * 2) = ab;
    float s = e.x * e.x + e.y * e.y;
    #pragma unroll
    for (int d = 1; d < 64; d <<= 1) s += __shfl_xor(s, d);
    if (lane == 0) sq[row] = s;
}

// Kernel 1b: per-class sumsq & count with wave pre-reduction (32 atomics/address).
__global__ __launch_bounds__(256) void agg_kernel(
    const float* __restrict__ sq, const int* __restrict__ labels,
    float* __restrict__ sumsq_c, int* __restrict__ cnt)
{
    int i = blockIdx.x * 256 + threadIdx.x;
    int lane = threadIdx.x & 63;
    float s = sq[i];
    int lab = labels[i];
    __shared__ float ss[NCLS];
    __shared__ int sc[NCLS];
    if (threadIdx.x < NCLS) { ss[threadIdx.x] = 0.f; sc[threadIdx.x] = 0; }
    __syncthreads();
    #pragma unroll
    for (int c = 0; c < NCLS; ++c) {
        float v = (lab == c) ? s : 0.f;
        int k = (lab == c) ? 1 : 0;
        #pragma unroll
        for (int d = 1; d < 64; d <<= 1) { v += __shfl_xor(v, d); k += __shfl_xor(k, d); }
        if (lane == 0) { atomicAdd(&ss[c], v); atomicAdd(&sc[c], k); }
    }
    __syncthreads();
    if (threadIdx.x < NCLS) {
        atomicAdd(&sumsq_c[threadIdx.x], ss[threadIdx.x]);
        atomicAdd(&cnt[threadIdx.x], sc[threadIdx.x]);
    }
}

// Kernel 2: s_c[c][d] = sum over class-c rows of emb[:, d]. Single pass over emb,
// branchless per-class accumulators (static indexing -> registers, rule #20).
__global__ __launch_bounds__(128) void class_sum_kernel(
    const float* __restrict__ emb, const int* __restrict__ labels,
    float* __restrict__ s_c)
{
    int base = blockIdx.x * 256;
    int d = threadIdx.x;
    float acc0 = 0.f, acc1 = 0.f, acc2 = 0.f, acc3 = 0.f, acc4 = 0.f;
    float acc5 = 0.f, acc6 = 0.f, acc7 = 0.f, acc8 = 0.f, acc9 = 0.f;
    for (int r = 0; r < 256; ++r) {
        int i = base + r;
        float v = emb[(size_t)i * DIM + d];
        int lab = labels[i];
        acc0 += (lab == 0) ? v : 0.f;
        acc1 += (lab == 1) ? v : 0.f;
        acc2 += (lab == 2) ? v : 0.f;
        acc3 += (lab == 3) ? v : 0.f;
        acc4 += (lab == 4) ? v : 0.f;
        acc5 += (lab == 5) ? v : 0.f;
        acc6 += (lab == 6) ? v : 0.f;
        acc7 += (lab == 7) ? v : 0.f;
        acc8 += (lab == 8) ? v : 0.f;
        acc9 += (lab == 9) ? v : 0.f;
    }
    atomicAdd(&s_c[0 * DIM + d], acc0);
    atomicAdd(&s_c[1 * DIM + d], acc1);
    atomicAdd(&s_c[2 * DIM + d], acc2);
    atomicAdd(&s_c[3 * DIM + d], acc3);
    atomicAdd(&s_c[4 * DIM + d], acc4);
    atomicAdd(&s_c[5 * DIM + d], acc5);
    atomicAdd(&s_c[6 * DIM + d], acc6);
    atomicAdd(&s_c[7 * DIM + d], acc7);
    atomicAdd(&s_c[8 * DIM + d], acc8);
    atomicAdd(&s_c[9 * DIM + d], acc9);
}

// Kernel 3: first-10 (smallest original index) members of class 0 and class 1.
__global__ void meta_kernel(const int* __restrict__ labels, int* __restrict__ lists)
{
    int lane = threadIdx.x & 63;
    for (int c = 0; c < 2; ++c) {
        int cnt = 0;
        for (int base = 0; base < N && cnt < 10; base += 64) {
            int lab = labels[base + lane];
            unsigned long long m = __ballot(lab == c);
            while (m && cnt < 10) {
                int b = __ffsll((unsigned long long)m) - 1;
                if (lane == 0) lists[c * 10 + cnt] = base + b;
                cnt++;
                m &= m - 1;
            }
        }
    }
}

// Kernel 4: masked Gram argmax. C = (-2E)·E^T via bf16 MFMA; val = sq[j] + C[i][j];
// per-row argmax over same-class cols, tie -> smallest j. One atomicMax per row per block.
__global__ __launch_bounds__(256, 2) void gram_kernel(
    const unsigned short* __restrict__ Abuf, const unsigned short* __restrict__ Bbuf,
    const float* __restrict__ sq, const int* __restrict__ labels,
    unsigned long long* __restrict__ packed)
{
    __shared__ __align__(16) unsigned short As[128 * 128]; // 32KB, full K, swizzled
    __shared__ __align__(16) unsigned short Bs[128 * 64];  // 16KB, half K, swizzled
    const int tid = threadIdx.x;
    const int lane = tid & 63;
    const int wid = tid >> 6;
    const int wr = wid >> 1, wc = wid & 1;       // 2x2 waves, each 64 rows x 64 cols
    const int rowbase = blockIdx.x * 128;
    const int stripbase = blockIdx.y * 1024;     // 8 strips x 1024 cols

    // Stage A once: tile is a contiguous 32KB block of Abuf.
    {
        const char* src = (const char*)(Abuf + (size_t)rowbase * DIM);
        #pragma unroll
        for (int p = 0; p < 8; ++p) {
            int o = (p * 256 + tid) * 16;
            uint4 v = *(const uint4*)(src + o);
            *(uint4*)((char*)As + (o ^ (((o >> 8) & 7) << 4))) = v;
        }
    }

    int labA[4][4];
    #pragma unroll
    for (int m = 0; m < 4; ++m)
        #pragma unroll
        for (int r = 0; r < 4; ++r)
            labA[m][r] = labels[rowbase + wr * 64 + m * 16 + (lane >> 4) * 4 + r];

    unsigned long long best[4][4];
    #pragma unroll
    for (int m = 0; m < 4; ++m)
        #pragma unroll
        for (int r = 0; r < 4; ++r) best[m][r] = 0ull;

    for (int ct = 0; ct < 8; ++ct) {
        const int colbase = stripbase + ct * 128;
        f32x4 acc[4][4];
        #pragma unroll
        for (int m = 0; m < 4; ++m)
            #pragma unroll
            for (int n = 0; n < 4; ++n) acc[m][n] = (f32x4){0.f, 0.f, 0.f, 0.f};

        #pragma unroll
        for (int kh = 0; kh < 2; ++kh) {
            __syncthreads();  // guard Bs overwrite vs prior reads
            #pragma unroll
            for (int p = 0; p < 4; ++p) {
                int o = (p * 256 + tid) * 16;
                int col = o >> 7, kb = o & 127;
                uint4 v = *(const uint4*)((const char*)(Bbuf + (size_t)(colbase + col) * DIM) + kh * 128 + kb);
                *(uint4*)((char*)Bs + (o ^ (((o >> 7) & 7) << 4))) = v;
            }
            __syncthreads();
            #pragma unroll
            for (int kk = 0; kk < 2; ++kk) {
                int kloc = kk * 32 + (lane >> 4) * 8;
                short8 a[4], b[4];
                #pragma unroll
                for (int m = 0; m < 4; ++m) {
                    int row = wr * 64 + m * 16 + (lane & 15);
                    int byt = row * 256 + (kh * 64 + kloc) * 2;
                    a[m] = *(const short8*)((const char*)As + (byt ^ ((row & 7) << 4)));
                }
                #pragma unroll
                for (int n = 0; n < 4; ++n) {
                    int col = wc * 64 + n * 16 + (lane & 15);
                    int byt = col * 128 + kloc * 2;
                    b[n] = *(const short8*)((const char*)Bs + (byt ^ ((col & 7) << 4)));
                }
                #pragma unroll
                for (int m = 0; m < 4; ++m)
                    #pragma unroll
                    for (int n = 0; n < 4; ++n)
                        acc[m][n] = __builtin_amdgcn_mfma_f32_16x16x32_bf16(a[m], b[n], acc[m][n], 0, 0, 0);
            }
        }
        // Epilogue: val = acc + sq[col]; masked packed-max update (registers only).
        #pragma unroll
        for (int n = 0; n < 4; ++n) {
            int colg = colbase + wc * 64 + n * 16 + (lane & 15);
            int labB = labels[colg];
            float sqv = sq[colg];
            unsigned long long idxbits = (unsigned long long)(~(unsigned)colg & 0xFFFFFFFFu);
            #pragma unroll
            for (int m = 0; m < 4; ++m)
                #pragma unroll
                for (int r = 0; r < 4; ++r) {
                    if (labA[m][r] == labB) {
                        float val = acc[m][n][r] + sqv;
                        unsigned u = __float_as_uint(val);
                        unsigned key = (u & 0x80000000u) ? ~u : (u | 0x80000000u);
                        unsigned long long pk = ((unsigned long long)key << 32) | idxbits;
                        if (pk > best[m][r]) best[m][r] = pk;
                    }
                }
        }
    }
    // Cross-lane reduce over the 16 columns-groups, then one atomic per row.
    #pragma unroll
    for (int m = 0; m < 4; ++m)
        #pragma unroll
        for (int r = 0; r < 4; ++r) {
            unsigned long long v = best[m][r];
            #pragma unroll
            for (int d = 1; d < 16; d <<= 1) {
                unsigned long long o = __shfl_xor(v, d);
                if (o > v) v = o;
            }
            if ((lane & 15) == 0 && v)
                atomicMax(&packed[rowbase + wr * 64 + m * 16 + (lane >> 4) * 4 + r], v);
        }
}

// Kernel 5: per-anchor j* via class aggregates, exact fp32 distances, loss sum.
__global__ __launch_bounds__(1024) void loss_kernel(
    const float* __restrict__ emb, const int* __restrict__ labels,
    const float* __restrict__ sq, const float* __restrict__ s_c,
    const float* __restrict__ sumsq_c, const int* __restrict__ cnt,
    const int* __restrict__ lists, const unsigned long long* __restrict__ packed,
    float* __restrict__ out)
{
    __shared__ float sc[NCLS * DIM];
    __shared__ float wsum[16];
    int tid = threadIdx.x;
    for (int p = tid; p < NCLS * DIM; p += 1024) sc[p] = s_c[p];
    __syncthreads();
    int wid = tid >> 6, lane = tid & 63;
    int i = blockIdx.x * 16 + wid;
    float2 e = *(const float2*)(emb + (size_t)i * DIM + lane * 2);
    float dots[NCLS];
    #pragma unroll
    for (int c = 0; c < NCLS; ++c)
        dots[c] = e.x * sc[c * DIM + lane * 2] + e.y * sc[c * DIM + lane * 2 + 1];
    #pragma unroll
    for (int d = 1; d < 64; d <<= 1) {
        #pragma unroll
        for (int c = 0; c < NCLS; ++c) dots[c] += __shfl_xor(dots[c], d);
    }
    float sqi = sq[i];
    int li = labels[i];
    // argmin_c negdist == argmax_c classsum (row-sum cancels); ties -> smallest c.
    float bestv = -3.4e38f; int js = 0;
    #pragma unroll
    for (int c = 0; c < NCLS; ++c) {
        float v = (float)cnt[c] * sqi + sumsq_c[c] - 2.f * dots[c];
        if (v > bestv) { bestv = v; js = c; }
    }
    int wn = lists[(li == 0 ? 10 : 0) + js];
    int wp = (int)(~(unsigned)packed[i]);  // low 32 bits hold ~j
    float2 ep = *(const float2*)(emb + (size_t)wp * DIM + lane * 2);
    float2 en = *(const float2*)(emb + (size_t)wn * DIM + lane * 2);
    float px = e.x - ep.x, py = e.y - ep.y;
    float nx = e.x - en.x, ny = e.y - en.y;
    float dp = px * px + py * py;
    float dn = nx * nx + ny * ny;
    #pragma unroll
    for (int d = 1; d < 64; d <<= 1) { dp += __shfl_xor(dp, d); dn += __shfl_xor(dn, d); }
    if (lane == 0) {
        float t = dp - dn + 1.0f;
        wsum[wid] = t > 0.f ? t : 0.f;
    }
    __syncthreads();
    if (tid == 0) {
        float s = 0.f;
        #pragma unroll
        for (int w = 0; w < 16; ++w) s += wsum[w];
        atomicAdd(out, s);
    }
}

extern "C" void kernel_launch(void* const* d_in, const int* in_sizes, int n_in,
                              void* d_out, int out_size, void* d_ws, size_t ws_size,
                              hipStream_t stream)
{
    const float* emb = (const float*)d_in[0];
    const int* labels = (const int*)d_in[1];
    char* ws = (char*)d_ws;

    unsigned short* Abuf = (unsigned short*)(ws);                                // 2 MB
    unsigned short* Bbuf = (unsigned short*)(ws + (size_t)2 * 1024 * 1024);      // 2 MB
    float* sq = (float*)(ws + (size_t)4 * 1024 * 1024);                          // 32 KB
    size_t zoff = (size_t)4 * 1024 * 1024 + 32 * 1024;
    unsigned long long* packed = (unsigned long long*)(ws + zoff);               // 64 KB
    float* s_c = (float*)(ws + zoff + 64 * 1024);                                // 5 KB
    float* sumsq_c = (float*)((char*)s_c + NCLS * DIM * sizeof(float));
    int* cnt = (int*)((char*)sumsq_c + NCLS * sizeof(float));
    int* lists = (int*)((char*)cnt + NCLS * sizeof(int));
    size_t zsz = 64 * 1024 + NCLS * DIM * sizeof(float) + NCLS * sizeof(float)
               + NCLS * sizeof(int) + 20 * sizeof(int);

    hipMemsetAsync(ws + zoff, 0, zsz, stream);
    hipMemsetAsync(d_out, 0, sizeof(float), stream);

    prep_kernel<<<2048, 256, 0, stream>>>(emb, Abuf, Bbuf, sq);
    agg_kernel<<<32, 256, 0, stream>>>(sq, labels, sumsq_c, cnt);
    class_sum_kernel<<<32, 128, 0, stream>>>(emb, labels, s_c);
    meta_kernel<<<1, 64, 0, stream>>>(labels, lists);
    gram_kernel<<<dim3(64, 8), 256, 0, stream>>>(Abuf, Bbuf, sq, labels, packed);
    loss_kernel<<<512, 1024, 0, stream>>>(emb, labels, sq, s_c, sumsq_c, cnt, lists, packed,
                                          (float*)d_out);
}

// Round 6
// 78.721 us; speedup vs baseline: 3.1587x; 1.3730x over previous
//
#include <hip/hip_runtime.h>
#include <stdint.h>

#define N 8192
#define DIM 128
#define NCLS 10
#define NPAD 9472        // max padded rows: sum ceil(n_c/128)*128 <= (64+10)*128
#define GRAM_GRID 512

typedef __attribute__((ext_vector_type(8))) short short8;
typedef __attribute__((ext_vector_type(4))) float f32x4;

static __device__ __forceinline__ unsigned short f2bf(float x) {
    unsigned u = __float_as_uint(x);
    unsigned r = (u + 0x7FFFu + ((u >> 16) & 1u)) >> 16;  // RNE
    return (unsigned short)r;
}

// K1: per-block per-class counts (ballot, no contention) + pad-slot init.
__global__ __launch_bounds__(256) void count_kernel(
    const int* __restrict__ labels, int* __restrict__ blkcnt,
    float* __restrict__ sqp, int* __restrict__ colidxp)
{
    int b = blockIdx.x, tid = threadIdx.x;
    for (int p = b * 256 + tid; p < NPAD; p += 40 * 256) {
        sqp[p] = -1e30f;
        colidxp[p] = -1;
    }
    if (b >= 32) return;
    int wid = tid >> 6, lane = tid & 63;
    int lab = labels[b * 256 + tid];
    __shared__ int swc[4][NCLS];
    #pragma unroll
    for (int c = 0; c < NCLS; ++c) {
        unsigned long long m = __ballot(lab == c);
        if (lane == 0) swc[wid][c] = __popcll(m);
    }
    __syncthreads();
    if (tid < NCLS)
        blkcnt[b * NCLS + tid] = swc[0][tid] + swc[1][tid] + swc[2][tid] + swc[3][tid];
}

// K2 (1 block, 64 threads): class totals -> cnt, padded offsets, per-block bases,
// work table of same-class (rowtile, coltile) pairs, plus the meta first-10 scan.
__global__ void offsets_kernel(
    const int* __restrict__ blkcnt, int* __restrict__ cnt,
    int* __restrict__ blockbase, int* __restrict__ work, int* __restrict__ nwork,
    const int* __restrict__ labels, int* __restrict__ lists)
{
    __shared__ int T[NCLS], off[NCLS], wb[NCLS + 1];
    int t = threadIdx.x;
    if (t < NCLS) {
        int s = 0;
        for (int b = 0; b < 32; ++b) s += blkcnt[b * NCLS + t];
        cnt[t] = s;
        T[t] = (s + 127) >> 7;
    }
    __syncthreads();
    if (t == 0) {
        int o = 0, w = 0;
        for (int c = 0; c < NCLS; ++c) {
            off[c] = o; o += T[c] << 7;
            wb[c] = w; w += T[c] * T[c];
        }
        wb[NCLS] = w;
        *nwork = w;
    }
    __syncthreads();
    if (t < NCLS) {
        int run = off[t];
        for (int b = 0; b < 32; ++b) {
            blockbase[b * NCLS + t] = run;
            run += blkcnt[b * NCLS + t];
        }
    }
    int W = wb[NCLS];
    for (int w = t; w < W; w += 64) {
        int c = 0;
        while (w >= wb[c + 1]) ++c;
        int loc = w - wb[c], Tc = T[c];
        int ti = loc / Tc, tj = loc - ti * Tc;
        work[w] = (off[c] + ti * 128) | ((off[c] + tj * 128) << 16);
    }
    // meta: first-10 (smallest index) members of class 0 and class 1 (1 wave).
    int lane = t;
    for (int c = 0; c < 2; ++c) {
        int k = 0;
        for (int base = 0; base < N && k < 10; base += 64) {
            int lab = labels[base + lane];
            unsigned long long m = __ballot(lab == c);
            while (m && k < 10) {
                int bpos = __ffsll((unsigned long long)m) - 1;
                if (lane == 0) lists[c * 10 + k] = base + bpos;
                k++;
                m &= m - 1;
            }
        }
    }
}

// K3: ballot-rank scatter -> posarr (row -> padded class-sorted slot), colidxp inverse.
__global__ __launch_bounds__(256) void perm_kernel(
    const int* __restrict__ labels, const int* __restrict__ blockbase,
    int* __restrict__ posarr, int* __restrict__ colidxp)
{
    int b = blockIdx.x, tid = threadIdx.x, wid = tid >> 6, lane = tid & 63;
    int i = b * 256 + tid;
    int lab = labels[i];
    __shared__ int swc[4][NCLS];
    unsigned long long mymask = 0;
    #pragma unroll
    for (int c = 0; c < NCLS; ++c) {
        unsigned long long m = __ballot(lab == c);
        if (lane == 0) swc[wid][c] = __popcll(m);
        if (lab == c) mymask = m;
    }
    __syncthreads();
    int base = blockbase[b * NCLS + lab];
    for (int w = 0; w < wid; ++w) base += swc[w][lab];
    int rank = __popcll(mymask & ((1ull << lane) - 1ull));
    int pos = base + rank;
    posarr[i] = pos;
    colidxp[pos] = i;
}

// K4: bf16(E) written directly in permuted order; sq (orig) + sqp (permuted).
// Single operand buffer: the -2 of D = sq_i + sq_j - 2*dot is folded into the
// gram epilogue (exact: scaling by -2 is an exponent shift in bf16 anyway).
__global__ __launch_bounds__(256) void prep_kernel(
    const float* __restrict__ emb, const int* __restrict__ posarr,
    unsigned short* __restrict__ Bperm,
    float* __restrict__ sq, float* __restrict__ sqp)
{
    int wid = threadIdx.x >> 6, lane = threadIdx.x & 63;
    int row = blockIdx.x * 4 + wid;
    int pos = posarr[row];
    const float2 e = *(const float2*)(emb + (size_t)row * DIM + lane * 2);
    unsigned bb = (unsigned)f2bf(e.x) | ((unsigned)f2bf(e.y) << 16);
    *(unsigned*)(Bperm + (size_t)pos * DIM + lane * 2) = bb;
    float s = e.x * e.x + e.y * e.y;
    #pragma unroll
    for (int d = 1; d < 64; d <<= 1) s += __shfl_xor(s, d);
    if (lane == 0) { sq[row] = s; sqp[pos] = s; }
}

// K5: per-class sumsq (wave pre-reduce -> shared -> 320 global atomics total).
__global__ __launch_bounds__(256) void agg_kernel(
    const float* __restrict__ sq, const int* __restrict__ labels,
    float* __restrict__ sumsq_c)
{
    int i = blockIdx.x * 256 + threadIdx.x;
    int lane = threadIdx.x & 63;
    float s = sq[i];
    int lab = labels[i];
    __shared__ float ss[NCLS];
    if (threadIdx.x < NCLS) ss[threadIdx.x] = 0.f;
    __syncthreads();
    #pragma unroll
    for (int c = 0; c < NCLS; ++c) {
        float v = (lab == c) ? s : 0.f;
        #pragma unroll
        for (int d = 1; d < 64; d <<= 1) v += __shfl_xor(v, d);
        if (lane == 0) atomicAdd(&ss[c], v);
    }
    __syncthreads();
    if (threadIdx.x < NCLS) atomicAdd(&sumsq_c[threadIdx.x], ss[threadIdx.x]);
}

// K6a/K6b: class d-sums, two-stage partial-store reduction (no atomics).
__global__ __launch_bounds__(256) void class_stage1(
    const float* __restrict__ emb, const int* __restrict__ labels,
    float* __restrict__ partial)
{
    int d = threadIdx.x & 127, h = threadIdx.x >> 7;
    int base = blockIdx.x * 128 + h * 64;
    float a0 = 0.f, a1 = 0.f, a2 = 0.f, a3 = 0.f, a4 = 0.f;
    float a5 = 0.f, a6 = 0.f, a7 = 0.f, a8 = 0.f, a9 = 0.f;
    for (int r = 0; r < 64; ++r) {
        int i = base + r;
        float v = emb[(size_t)i * DIM + d];
        int lab = labels[i];
        a0 += (lab == 0) ? v : 0.f;  a1 += (lab == 1) ? v : 0.f;
        a2 += (lab == 2) ? v : 0.f;  a3 += (lab == 3) ? v : 0.f;
        a4 += (lab == 4) ? v : 0.f;  a5 += (lab == 5) ? v : 0.f;
        a6 += (lab == 6) ? v : 0.f;  a7 += (lab == 7) ? v : 0.f;
        a8 += (lab == 8) ? v : 0.f;  a9 += (lab == 9) ? v : 0.f;
    }
    int vb = blockIdx.x * 2 + h;
    float* p = partial + (size_t)vb * (NCLS * DIM) + d;
    p[0 * DIM] = a0; p[1 * DIM] = a1; p[2 * DIM] = a2; p[3 * DIM] = a3; p[4 * DIM] = a4;
    p[5 * DIM] = a5; p[6 * DIM] = a6; p[7 * DIM] = a7; p[8 * DIM] = a8; p[9 * DIM] = a9;
}

__global__ __launch_bounds__(128) void class_stage2(
    const float* __restrict__ partial, float* __restrict__ s_c)
{
    int c = blockIdx.x, d = threadIdx.x;
    float s = 0.f;
    for (int vb = 0; vb < 128; ++vb)
        s += partial[(size_t)vb * (NCLS * DIM) + c * DIM + d];
    s_c[c * DIM + d] = s;
}

// K7: class-blocked Gram argmax. Persistent blocks grid-stride a work table of
// same-class 128x128 tile pairs; K=128 in one shot; both operands from Bperm.
__global__ __launch_bounds__(256, 2) void gram_kernel(
    const unsigned short* __restrict__ Bperm,
    const float* __restrict__ sqp, const int* __restrict__ colidxp,
    const int* __restrict__ work, const int* __restrict__ nwork_p,
    unsigned long long* __restrict__ packed)
{
    __shared__ __align__(16) unsigned short As[128 * 128]; // 32KB swizzled
    __shared__ __align__(16) unsigned short Bs[128 * 128]; // 32KB swizzled
    const int tid = threadIdx.x;
    const int lane = tid & 63;
    const int wid = tid >> 6;
    const int wr = wid >> 1, wc = wid & 1;   // 2x2 waves, 64x64 output each
    const int nwork = *nwork_p;

    for (int w = blockIdx.x; w < nwork; w += GRAM_GRID) {
        int item = work[w];
        int rowbase = item & 0xFFFF, colbase = item >> 16;

        __syncthreads();  // prior iteration's ds_reads complete before overwrite
        const char* asrc = (const char*)(Bperm + (size_t)rowbase * DIM);
        const char* bsrc = (const char*)(Bperm + (size_t)colbase * DIM);
        #pragma unroll
        for (int p = 0; p < 8; ++p) {
            int o = (p * 256 + tid) * 16;
            uint4 va = *(const uint4*)(asrc + o);
            uint4 vb = *(const uint4*)(bsrc + o);
            int sw = o ^ (((o >> 8) & 7) << 4);
            *(uint4*)((char*)As + sw) = va;
            *(uint4*)((char*)Bs + sw) = vb;
        }
        __syncthreads();

        f32x4 acc[4][4];
        #pragma unroll
        for (int m = 0; m < 4; ++m)
            #pragma unroll
            for (int n = 0; n < 4; ++n) acc[m][n] = (f32x4){0.f, 0.f, 0.f, 0.f};

        #pragma unroll
        for (int kk = 0; kk < 4; ++kk) {
            int kloc = kk * 32 + (lane >> 4) * 8;
            short8 a[4], b[4];
            #pragma unroll
            for (int m = 0; m < 4; ++m) {
                int row = wr * 64 + m * 16 + (lane & 15);
                int byt = row * 256 + kloc * 2;
                a[m] = *(const short8*)((const char*)As + (byt ^ ((row & 7) << 4)));
            }
            #pragma unroll
            for (int n = 0; n < 4; ++n) {
                int col = wc * 64 + n * 16 + (lane & 15);
                int byt = col * 256 + kloc * 2;
                b[n] = *(const short8*)((const char*)Bs + (byt ^ ((col & 7) << 4)));
            }
            #pragma unroll
            for (int m = 0; m < 4; ++m)
                #pragma unroll
                for (int n = 0; n < 4; ++n)
                    acc[m][n] = __builtin_amdgcn_mfma_f32_16x16x32_bf16(a[m], b[n], acc[m][n], 0, 0, 0);
        }

        // Epilogue: val = sqp[col] - 2*dot; packed-max with original col index.
        unsigned long long best[4][4];
        #pragma unroll
        for (int m = 0; m < 4; ++m)
            #pragma unroll
            for (int r = 0; r < 4; ++r) best[m][r] = 0ull;

        #pragma unroll
        for (int n = 0; n < 4; ++n) {
            int colg = colbase + wc * 64 + n * 16 + (lane & 15);
            float sqv = sqp[colg];
            int cidx = colidxp[colg];
            unsigned long long idxbits = (unsigned long long)(~(unsigned)cidx & 0xFFFFFFFFu);
            #pragma unroll
            for (int m = 0; m < 4; ++m)
                #pragma unroll
                for (int r = 0; r < 4; ++r) {
                    float val = fmaf(-2.f, acc[m][n][r], sqv);
                    unsigned u = __float_as_uint(val);
                    unsigned key = (u & 0x80000000u) ? ~u : (u | 0x80000000u);
                    unsigned long long pk = ((unsigned long long)key << 32) | idxbits;
                    if (pk > best[m][r]) best[m][r] = pk;
                }
        }
        #pragma unroll
        for (int m = 0; m < 4; ++m)
            #pragma unroll
            for (int r = 0; r < 4; ++r) {
                unsigned long long v = best[m][r];
                #pragma unroll
                for (int d = 1; d < 16; d <<= 1) {
                    unsigned long long o = __shfl_xor(v, d);
                    if (o > v) v = o;
                }
                if ((lane & 15) == 0) {
                    int rowg = rowbase + wr * 64 + m * 16 + (lane >> 4) * 4 + r;
                    int ridx = colidxp[rowg];
                    if (ridx >= 0) atomicMax(&packed[ridx], v);
                }
            }
    }
}

// K8: per-anchor j* via class aggregates, exact fp32 distances, loss sum.
__global__ __launch_bounds__(1024) void loss_kernel(
    const float* __restrict__ emb, const int* __restrict__ labels,
    const float* __restrict__ sq, const float* __restrict__ s_c,
    const float* __restrict__ sumsq_c, const int* __restrict__ cnt,
    const int* __restrict__ lists, const unsigned long long* __restrict__ packed,
    float* __restrict__ out)
{
    __shared__ float sc[NCLS * DIM];
    __shared__ float wsum[16];
    int tid = threadIdx.x;
    for (int p = tid; p < NCLS * DIM; p += 1024) sc[p] = s_c[p];
    __syncthreads();
    int wid = tid >> 6, lane = tid & 63;
    int i = blockIdx.x * 16 + wid;
    float2 e = *(const float2*)(emb + (size_t)i * DIM + lane * 2);
    float dots[NCLS];
    #pragma unroll
    for (int c = 0; c < NCLS; ++c)
        dots[c] = e.x * sc[c * DIM + lane * 2] + e.y * sc[c * DIM + lane * 2 + 1];
    #pragma unroll
    for (int d = 1; d < 64; d <<= 1) {
        #pragma unroll
        for (int c = 0; c < NCLS; ++c) dots[c] += __shfl_xor(dots[c], d);
    }
    float sqi = sq[i];
    int li = labels[i];
    float bestv = -3.4e38f; int js = 0;
    #pragma unroll
    for (int c = 0; c < NCLS; ++c) {
        float v = (float)cnt[c] * sqi + sumsq_c[c] - 2.f * dots[c];
        if (v > bestv) { bestv = v; js = c; }
    }
    int wn = lists[(li == 0 ? 10 : 0) + js];
    int wp = (int)(~(unsigned)packed[i]);
    float2 ep = *(const float2*)(emb + (size_t)wp * DIM + lane * 2);
    float2 en = *(const float2*)(emb + (size_t)wn * DIM + lane * 2);
    float px = e.x - ep.x, py = e.y - ep.y;
    float nx = e.x - en.x, ny = e.y - en.y;
    float dp = px * px + py * py;
    float dn = nx * nx + ny * ny;
    #pragma unroll
    for (int d = 1; d < 64; d <<= 1) { dp += __shfl_xor(dp, d); dn += __shfl_xor(dn, d); }
    if (lane == 0) {
        float t = dp - dn + 1.0f;
        wsum[wid] = t > 0.f ? t : 0.f;
    }
    __syncthreads();
    if (tid == 0) {
        float s = 0.f;
        #pragma unroll
        for (int w = 0; w < 16; ++w) s += wsum[w];
        atomicAdd(out, s);
    }
}

extern "C" void kernel_launch(void* const* d_in, const int* in_sizes, int n_in,
                              void* d_out, int out_size, void* d_ws, size_t ws_size,
                              hipStream_t stream)
{
    const float* emb = (const float*)d_in[0];
    const int* labels = (const int*)d_in[1];
    char* ws = (char*)d_ws;

    // Layout (bytes, 256-aligned). Total footprint 3,328,000 B (~3.3 MB).
    unsigned short* Bperm  = (unsigned short*)(ws + 0);                  // 2,424,832
    float* sq              = (float*)(ws + 2424832);                     // 32,768
    float* sqp             = (float*)(ws + 2457600);                     // 37,888 (init'd by count_kernel)
    int*   colidxp         = (int*)  (ws + 2495488);                     // 37,888 (init'd by count_kernel)
    int*   posarr          = (int*)  (ws + 2533376);                     // 32,768 (fully written)
    unsigned long long* packed = (unsigned long long*)(ws + 2566144);    // 65,536 (memset 0)
    int*   blkcnt          = (int*)  (ws + 2631680);                     // 1,280
    int*   blockbase       = (int*)  (ws + 2632960);                     // 1,280
    int*   nwork           = (int*)  (ws + 2634240);                     // 256
    int*   work            = (int*)  (ws + 2634496);                     // 32,768
    float* partial         = (float*)(ws + 2667264);                     // 655,360
    float* s_c             = (float*)(ws + 3322624);                     // 5,120
    float* sumsq_c         = (float*)(ws + 3327744);                     // 64 (memset 0)
    int*   cnt             = (int*)  (ws + 3327808);                     // 64
    int*   lists           = (int*)  (ws + 3327872);                     // 128

    // Zero: Bperm pads (pad rows must be 0.0 so pad dot == 0), packed, sumsq_c.
    hipMemsetAsync(ws, 0, 2424832, stream);
    hipMemsetAsync(ws + 2566144, 0, 65536, stream);
    hipMemsetAsync(ws + 3327744, 0, 64, stream);
    hipMemsetAsync(d_out, 0, sizeof(float), stream);

    count_kernel<<<40, 256, 0, stream>>>(labels, blkcnt, sqp, colidxp);
    offsets_kernel<<<1, 64, 0, stream>>>(blkcnt, cnt, blockbase, work, nwork, labels, lists);
    perm_kernel<<<32, 256, 0, stream>>>(labels, blockbase, posarr, colidxp);
    prep_kernel<<<2048, 256, 0, stream>>>(emb, posarr, Bperm, sq, sqp);
    agg_kernel<<<32, 256, 0, stream>>>(sq, labels, sumsq_c);
    class_stage1<<<64, 256, 0, stream>>>(emb, labels, partial);
    class_stage2<<<10, 128, 0, stream>>>(partial, s_c);
    gram_kernel<<<GRAM_GRID, 256, 0, stream>>>(Bperm, sqp, colidxp, work, nwork, packed);
    loss_kernel<<<512, 1024, 0, stream>>>(emb, labels, sq, s_c, sumsq_c, cnt, lists, packed,
                                          (float*)d_out);
}

// Round 7
// 71.516 us; speedup vs baseline: 3.4769x; 1.1007x over previous
//
#include <hip/hip_runtime.h>
#include <stdint.h>

#define N 8192
#define DIM 128
#define NCLS 10
#define NPAD 9472        // max padded rows: sum ceil(n_c/128)*128 <= (64+10)*128
#define GRAM_GRID 512

typedef __attribute__((ext_vector_type(8))) short short8;
typedef __attribute__((ext_vector_type(4))) float f32x4;

static __device__ __forceinline__ unsigned short f2bf(float x) {
    unsigned u = __float_as_uint(x);
    unsigned r = (u + 0x7FFFu + ((u >> 16) & 1u)) >> 16;  // RNE
    return (unsigned short)r;
}

// K1: per-block per-class counts (ballot, no contention) + ALL buffer zero-init
// (replaces every hipMemsetAsync: Bperm, packed, sumsq_c, d_out, sqp/colidxp pads).
__global__ __launch_bounds__(256) void count_kernel(
    const int* __restrict__ labels, int* __restrict__ blkcnt,
    float* __restrict__ sqp, int* __restrict__ colidxp,
    uint4* __restrict__ Bperm4, unsigned long long* __restrict__ packed,
    float* __restrict__ sumsq_c, float* __restrict__ out)
{
    int b = blockIdx.x, tid = threadIdx.x;
    int gt = b * 256 + tid;
    const uint4 z = {0u, 0u, 0u, 0u};
    for (int p = gt; p < 151552; p += 512 * 256) Bperm4[p] = z;   // 2,424,832 B
    if (gt < 8192) packed[gt] = 0ull;
    if (gt < NPAD) { sqp[gt] = -1e30f; colidxp[gt] = -1; }
    if (gt < NCLS) sumsq_c[gt] = 0.f;
    if (gt == 0) *out = 0.f;

    if (b >= 32) return;
    int wid = tid >> 6, lane = tid & 63;
    int lab = labels[b * 256 + tid];
    __shared__ int swc[4][NCLS];
    #pragma unroll
    for (int c = 0; c < NCLS; ++c) {
        unsigned long long m = __ballot(lab == c);
        if (lane == 0) swc[wid][c] = __popcll(m);
    }
    __syncthreads();
    if (tid < NCLS)
        blkcnt[b * NCLS + tid] = swc[0][tid] + swc[1][tid] + swc[2][tid] + swc[3][tid];
}

// K2 (1 block, 64 threads): class totals -> cnt, padded offsets, per-block bases,
// work table of same-class (rowtile, coltile) pairs, plus the meta first-10 scan.
__global__ void offsets_kernel(
    const int* __restrict__ blkcnt, int* __restrict__ cnt,
    int* __restrict__ blockbase, int* __restrict__ work, int* __restrict__ nwork,
    const int* __restrict__ labels, int* __restrict__ lists)
{
    __shared__ int T[NCLS], off[NCLS], wb[NCLS + 1];
    int t = threadIdx.x;
    if (t < NCLS) {
        int s = 0;
        for (int b = 0; b < 32; ++b) s += blkcnt[b * NCLS + t];
        cnt[t] = s;
        T[t] = (s + 127) >> 7;
    }
    __syncthreads();
    if (t == 0) {
        int o = 0, w = 0;
        for (int c = 0; c < NCLS; ++c) {
            off[c] = o; o += T[c] << 7;
            wb[c] = w; w += T[c] * T[c];
        }
        wb[NCLS] = w;
        *nwork = w;
    }
    __syncthreads();
    if (t < NCLS) {
        int run = off[t];
        for (int b = 0; b < 32; ++b) {
            blockbase[b * NCLS + t] = run;
            run += blkcnt[b * NCLS + t];
        }
    }
    int W = wb[NCLS];
    for (int w = t; w < W; w += 64) {
        int c = 0;
        while (w >= wb[c + 1]) ++c;
        int loc = w - wb[c], Tc = T[c];
        int ti = loc / Tc, tj = loc - ti * Tc;
        work[w] = (off[c] + ti * 128) | ((off[c] + tj * 128) << 16);
    }
    // meta: first-10 (smallest index) members of class 0 and class 1 (1 wave).
    int lane = t;
    for (int c = 0; c < 2; ++c) {
        int k = 0;
        for (int base = 0; base < N && k < 10; base += 64) {
            int lab = labels[base + lane];
            unsigned long long m = __ballot(lab == c);
            while (m && k < 10) {
                int bpos = __ffsll((unsigned long long)m) - 1;
                if (lane == 0) lists[c * 10 + k] = base + bpos;
                k++;
                m &= m - 1;
            }
        }
    }
}

// K3: ballot-rank scatter -> posarr (row -> padded class-sorted slot), colidxp inverse.
__global__ __launch_bounds__(256) void perm_kernel(
    const int* __restrict__ labels, const int* __restrict__ blockbase,
    int* __restrict__ posarr, int* __restrict__ colidxp)
{
    int b = blockIdx.x, tid = threadIdx.x, wid = tid >> 6, lane = tid & 63;
    int i = b * 256 + tid;
    int lab = labels[i];
    __shared__ int swc[4][NCLS];
    unsigned long long mymask = 0;
    #pragma unroll
    for (int c = 0; c < NCLS; ++c) {
        unsigned long long m = __ballot(lab == c);
        if (lane == 0) swc[wid][c] = __popcll(m);
        if (lab == c) mymask = m;
    }
    __syncthreads();
    int base = blockbase[b * NCLS + lab];
    for (int w = 0; w < wid; ++w) base += swc[w][lab];
    int rank = __popcll(mymask & ((1ull << lane) - 1ull));
    int pos = base + rank;
    posarr[i] = pos;
    colidxp[pos] = i;
}

// K4: bf16(E) written directly in permuted order; sq (orig) + sqp (permuted).
// Single operand buffer: the -2 of D = sq_i + sq_j - 2*dot is folded into the
// gram epilogue (exact: scaling by -2 is an exponent shift in bf16 anyway).
__global__ __launch_bounds__(256) void prep_kernel(
    const float* __restrict__ emb, const int* __restrict__ posarr,
    unsigned short* __restrict__ Bperm,
    float* __restrict__ sq, float* __restrict__ sqp)
{
    int wid = threadIdx.x >> 6, lane = threadIdx.x & 63;
    int row = blockIdx.x * 4 + wid;
    int pos = posarr[row];
    const float2 e = *(const float2*)(emb + (size_t)row * DIM + lane * 2);
    unsigned bb = (unsigned)f2bf(e.x) | ((unsigned)f2bf(e.y) << 16);
    *(unsigned*)(Bperm + (size_t)pos * DIM + lane * 2) = bb;
    float s = e.x * e.x + e.y * e.y;
    #pragma unroll
    for (int d = 1; d < 64; d <<= 1) s += __shfl_xor(s, d);
    if (lane == 0) { sq[row] = s; sqp[pos] = s; }
}

// K5: per-class sumsq (wave pre-reduce -> shared -> 320 global atomics total).
__global__ __launch_bounds__(256) void agg_kernel(
    const float* __restrict__ sq, const int* __restrict__ labels,
    float* __restrict__ sumsq_c)
{
    int i = blockIdx.x * 256 + threadIdx.x;
    int lane = threadIdx.x & 63;
    float s = sq[i];
    int lab = labels[i];
    __shared__ float ss[NCLS];
    if (threadIdx.x < NCLS) ss[threadIdx.x] = 0.f;
    __syncthreads();
    #pragma unroll
    for (int c = 0; c < NCLS; ++c) {
        float v = (lab == c) ? s : 0.f;
        #pragma unroll
        for (int d = 1; d < 64; d <<= 1) v += __shfl_xor(v, d);
        if (lane == 0) atomicAdd(&ss[c], v);
    }
    __syncthreads();
    if (threadIdx.x < NCLS) atomicAdd(&sumsq_c[threadIdx.x], ss[threadIdx.x]);
}

// K6a/K6b: class d-sums, two-stage partial-store reduction (no atomics).
__global__ __launch_bounds__(256) void class_stage1(
    const float* __restrict__ emb, const int* __restrict__ labels,
    float* __restrict__ partial)
{
    int d = threadIdx.x & 127, h = threadIdx.x >> 7;
    int base = blockIdx.x * 128 + h * 64;
    float a0 = 0.f, a1 = 0.f, a2 = 0.f, a3 = 0.f, a4 = 0.f;
    float a5 = 0.f, a6 = 0.f, a7 = 0.f, a8 = 0.f, a9 = 0.f;
    for (int r = 0; r < 64; ++r) {
        int i = base + r;
        float v = emb[(size_t)i * DIM + d];
        int lab = labels[i];
        a0 += (lab == 0) ? v : 0.f;  a1 += (lab == 1) ? v : 0.f;
        a2 += (lab == 2) ? v : 0.f;  a3 += (lab == 3) ? v : 0.f;
        a4 += (lab == 4) ? v : 0.f;  a5 += (lab == 5) ? v : 0.f;
        a6 += (lab == 6) ? v : 0.f;  a7 += (lab == 7) ? v : 0.f;
        a8 += (lab == 8) ? v : 0.f;  a9 += (lab == 9) ? v : 0.f;
    }
    int vb = blockIdx.x * 2 + h;
    float* p = partial + (size_t)vb * (NCLS * DIM) + d;
    p[0 * DIM] = a0; p[1 * DIM] = a1; p[2 * DIM] = a2; p[3 * DIM] = a3; p[4 * DIM] = a4;
    p[5 * DIM] = a5; p[6 * DIM] = a6; p[7 * DIM] = a7; p[8 * DIM] = a8; p[9 * DIM] = a9;
}

__global__ __launch_bounds__(128) void class_stage2(
    const float* __restrict__ partial, float* __restrict__ s_c)
{
    int c = blockIdx.x, d = threadIdx.x;
    float s = 0.f;
    for (int vb = 0; vb < 128; ++vb)
        s += partial[(size_t)vb * (NCLS * DIM) + c * DIM + d];
    s_c[c * DIM + d] = s;
}

// K7: class-blocked Gram argmax. Persistent blocks grid-stride a work table of
// same-class 128x128 tile pairs; K=128 in one shot; both operands from Bperm.
__global__ __launch_bounds__(256, 2) void gram_kernel(
    const unsigned short* __restrict__ Bperm,
    const float* __restrict__ sqp, const int* __restrict__ colidxp,
    const int* __restrict__ work, const int* __restrict__ nwork_p,
    unsigned long long* __restrict__ packed)
{
    __shared__ __align__(16) unsigned short As[128 * 128]; // 32KB swizzled
    __shared__ __align__(16) unsigned short Bs[128 * 128]; // 32KB swizzled
    const int tid = threadIdx.x;
    const int lane = tid & 63;
    const int wid = tid >> 6;
    const int wr = wid >> 1, wc = wid & 1;   // 2x2 waves, 64x64 output each
    const int nwork = *nwork_p;

    for (int w = blockIdx.x; w < nwork; w += GRAM_GRID) {
        int item = work[w];
        int rowbase = item & 0xFFFF, colbase = item >> 16;

        __syncthreads();  // prior iteration's ds_reads complete before overwrite
        const char* asrc = (const char*)(Bperm + (size_t)rowbase * DIM);
        const char* bsrc = (const char*)(Bperm + (size_t)colbase * DIM);
        #pragma unroll
        for (int p = 0; p < 8; ++p) {
            int o = (p * 256 + tid) * 16;
            uint4 va = *(const uint4*)(asrc + o);
            uint4 vb = *(const uint4*)(bsrc + o);
            int sw = o ^ (((o >> 8) & 7) << 4);
            *(uint4*)((char*)As + sw) = va;
            *(uint4*)((char*)Bs + sw) = vb;
        }
        __syncthreads();

        f32x4 acc[4][4];
        #pragma unroll
        for (int m = 0; m < 4; ++m)
            #pragma unroll
            for (int n = 0; n < 4; ++n) acc[m][n] = (f32x4){0.f, 0.f, 0.f, 0.f};

        #pragma unroll
        for (int kk = 0; kk < 4; ++kk) {
            int kloc = kk * 32 + (lane >> 4) * 8;
            short8 a[4], b[4];
            #pragma unroll
            for (int m = 0; m < 4; ++m) {
                int row = wr * 64 + m * 16 + (lane & 15);
                int byt = row * 256 + kloc * 2;
                a[m] = *(const short8*)((const char*)As + (byt ^ ((row & 7) << 4)));
            }
            #pragma unroll
            for (int n = 0; n < 4; ++n) {
                int col = wc * 64 + n * 16 + (lane & 15);
                int byt = col * 256 + kloc * 2;
                b[n] = *(const short8*)((const char*)Bs + (byt ^ ((col & 7) << 4)));
            }
            #pragma unroll
            for (int m = 0; m < 4; ++m)
                #pragma unroll
                for (int n = 0; n < 4; ++n)
                    acc[m][n] = __builtin_amdgcn_mfma_f32_16x16x32_bf16(a[m], b[n], acc[m][n], 0, 0, 0);
        }

        // Epilogue: val = sqp[col] - 2*dot; packed-max with original col index.
        unsigned long long best[4][4];
        #pragma unroll
        for (int m = 0; m < 4; ++m)
            #pragma unroll
            for (int r = 0; r < 4; ++r) best[m][r] = 0ull;

        #pragma unroll
        for (int n = 0; n < 4; ++n) {
            int colg = colbase + wc * 64 + n * 16 + (lane & 15);
            float sqv = sqp[colg];
            int cidx = colidxp[colg];
            unsigned long long idxbits = (unsigned long long)(~(unsigned)cidx & 0xFFFFFFFFu);
            #pragma unroll
            for (int m = 0; m < 4; ++m)
                #pragma unroll
                for (int r = 0; r < 4; ++r) {
                    float val = fmaf(-2.f, acc[m][n][r], sqv);
                    unsigned u = __float_as_uint(val);
                    unsigned key = (u & 0x80000000u) ? ~u : (u | 0x80000000u);
                    unsigned long long pk = ((unsigned long long)key << 32) | idxbits;
                    if (pk > best[m][r]) best[m][r] = pk;
                }
        }
        #pragma unroll
        for (int m = 0; m < 4; ++m)
            #pragma unroll
            for (int r = 0; r < 4; ++r) {
                unsigned long long v = best[m][r];
                #pragma unroll
                for (int d = 1; d < 16; d <<= 1) {
                    unsigned long long o = __shfl_xor(v, d);
                    if (o > v) v = o;
                }
                if ((lane & 15) == 0) {
                    int rowg = rowbase + wr * 64 + m * 16 + (lane >> 4) * 4 + r;
                    int ridx = colidxp[rowg];
                    if (ridx >= 0) atomicMax(&packed[ridx], v);
                }
            }
    }
}

// K8: per-anchor j* via class aggregates, exact fp32 distances, loss sum.
__global__ __launch_bounds__(1024) void loss_kernel(
    const float* __restrict__ emb, const int* __restrict__ labels,
    const float* __restrict__ sq, const float* __restrict__ s_c,
    const float* __restrict__ sumsq_c, const int* __restrict__ cnt,
    const int* __restrict__ lists, const unsigned long long* __restrict__ packed,
    float* __restrict__ out)
{
    __shared__ float sc[NCLS * DIM];
    __shared__ float wsum[16];
    int tid = threadIdx.x;
    for (int p = tid; p < NCLS * DIM; p += 1024) sc[p] = s_c[p];
    __syncthreads();
    int wid = tid >> 6, lane = tid & 63;
    int i = blockIdx.x * 16 + wid;
    float2 e = *(const float2*)(emb + (size_t)i * DIM + lane * 2);
    float dots[NCLS];
    #pragma unroll
    for (int c = 0; c < NCLS; ++c)
        dots[c] = e.x * sc[c * DIM + lane * 2] + e.y * sc[c * DIM + lane * 2 + 1];
    #pragma unroll
    for (int d = 1; d < 64; d <<= 1) {
        #pragma unroll
        for (int c = 0; c < NCLS; ++c) dots[c] += __shfl_xor(dots[c], d);
    }
    float sqi = sq[i];
    int li = labels[i];
    float bestv = -3.4e38f; int js = 0;
    #pragma unroll
    for (int c = 0; c < NCLS; ++c) {
        float v = (float)cnt[c] * sqi + sumsq_c[c] - 2.f * dots[c];
        if (v > bestv) { bestv = v; js = c; }
    }
    int wn = lists[(li == 0 ? 10 : 0) + js];
    int wp = (int)(~(unsigned)packed[i]);
    float2 ep = *(const float2*)(emb + (size_t)wp * DIM + lane * 2);
    float2 en = *(const float2*)(emb + (size_t)wn * DIM + lane * 2);
    float px = e.x - ep.x, py = e.y - ep.y;
    float nx = e.x - en.x, ny = e.y - en.y;
    float dp = px * px + py * py;
    float dn = nx * nx + ny * ny;
    #pragma unroll
    for (int d = 1; d < 64; d <<= 1) { dp += __shfl_xor(dp, d); dn += __shfl_xor(dn, d); }
    if (lane == 0) {
        float t = dp - dn + 1.0f;
        wsum[wid] = t > 0.f ? t : 0.f;
    }
    __syncthreads();
    if (tid == 0) {
        float s = 0.f;
        #pragma unroll
        for (int w = 0; w < 16; ++w) s += wsum[w];
        atomicAdd(out, s);
    }
}

extern "C" void kernel_launch(void* const* d_in, const int* in_sizes, int n_in,
                              void* d_out, int out_size, void* d_ws, size_t ws_size,
                              hipStream_t stream)
{
    const float* emb = (const float*)d_in[0];
    const int* labels = (const int*)d_in[1];
    char* ws = (char*)d_ws;

    // Layout (bytes, 256-aligned). Total footprint 3,328,000 B (~3.3 MB).
    unsigned short* Bperm  = (unsigned short*)(ws + 0);                  // 2,424,832
    float* sq              = (float*)(ws + 2424832);                     // 32,768
    float* sqp             = (float*)(ws + 2457600);                     // 37,888 (init'd by count_kernel)
    int*   colidxp         = (int*)  (ws + 2495488);                     // 37,888 (init'd by count_kernel)
    int*   posarr          = (int*)  (ws + 2533376);                     // 32,768 (fully written)
    unsigned long long* packed = (unsigned long long*)(ws + 2566144);    // 65,536 (init'd by count_kernel)
    int*   blkcnt          = (int*)  (ws + 2631680);                     // 1,280
    int*   blockbase       = (int*)  (ws + 2632960);                     // 1,280
    int*   nwork           = (int*)  (ws + 2634240);                     // 256
    int*   work            = (int*)  (ws + 2634496);                     // 32,768
    float* partial         = (float*)(ws + 2667264);                     // 655,360
    float* s_c             = (float*)(ws + 3322624);                     // 5,120
    float* sumsq_c         = (float*)(ws + 3327744);                     // 64 (init'd by count_kernel)
    int*   cnt             = (int*)  (ws + 3327808);                     // 64
    int*   lists           = (int*)  (ws + 3327872);                     // 128

    // No hipMemsetAsync: count_kernel performs all zero-init (Bperm pads must be
    // 0.0 so pad dots == 0; packed/sumsq_c/d_out accumulate via atomics).
    count_kernel<<<512, 256, 0, stream>>>(labels, blkcnt, sqp, colidxp,
                                          (uint4*)Bperm, packed, sumsq_c, (float*)d_out);
    offsets_kernel<<<1, 64, 0, stream>>>(blkcnt, cnt, blockbase, work, nwork, labels, lists);
    perm_kernel<<<32, 256, 0, stream>>>(labels, blockbase, posarr, colidxp);
    prep_kernel<<<2048, 256, 0, stream>>>(emb, posarr, Bperm, sq, sqp);
    agg_kernel<<<32, 256, 0, stream>>>(sq, labels, sumsq_c);
    class_stage1<<<64, 256, 0, stream>>>(emb, labels, partial);
    class_stage2<<<10, 128, 0, stream>>>(partial, s_c);
    gram_kernel<<<GRAM_GRID, 256, 0, stream>>>(Bperm, sqp, colidxp, work, nwork, packed);
    loss_kernel<<<512, 1024, 0, stream>>>(emb, labels, sq, s_c, sumsq_c, cnt, lists, packed,
                                          (float*)d_out);
}